// Round 4
// baseline (462.896 us; speedup 1.0000x reference)
//
#include <hip/hip_runtime.h>
#include <hip/hip_bf16.h>
#include <math.h>

// Problem constants: B=16, H=32, KV=8, D=128, BS=16, MAXLEN=4096
#define B_ 16
#define H_ 32
#define KVH_ 8
#define D_ 128
#define BS_ 16
#define NBLK_ 256
#define GQA_R 4          // H / KV
#define LOCALB 16        // LOCAL_BLOCKS
#define VSTRIDE 8        // VERT_STRIDE (head_sliding_step = max(1, 8/32) = 1)
#define NSPLIT_ 16

// K layout: [NB][KVH][D/4][BS][4] f32 -> K[t][d] at (((nb*8+kvh)*32 + d/4)*16 + t)*4 + d%4
// V layout: [NB][KVH][D][BS]   f32 -> V[d][t] at  ((nb*8+kvh)*128 + d)*16 + t
// Both are 2048 floats (8KB) per (nb,kvh).

// Shared body for the split (partial) and direct paths.
// NOTE: no template parameters with commas -> demangled names stay CSV-friendly.

__device__ __forceinline__ void attn_body(
    const float* __restrict__ qg, const float* __restrict__ kc,
    const float* __restrict__ vc, const int* __restrict__ block_tables,
    const int* __restrict__ ctx_lens,
    int nsplit, int split, int b, int kvh,
    float* __restrict__ po, float* __restrict__ pml, float* __restrict__ out,
    bool direct)
{
  const int wid  = threadIdx.x >> 6;   // wave = head-in-group
  const int lane = threadIdx.x & 63;
  const int t    = lane >> 2;          // token 0..15
  const int c    = lane & 3;           // 32-dim chunk 0..3
  const int h    = kvh * GQA_R + wid;

  const int past_len = ctx_lens[b] - 1;
  const int q_pbid   = past_len >> 4;
  const int lo_start = max(0, q_pbid - (LOCALB - 1));
  const int nloc     = q_pbid - lo_start + 1;
  const int v_res    = (VSTRIDE - ((h + 1) & (VSTRIDE - 1))) & (VSTRIDE - 1);
  const int ndist    = (lo_start > v_res) ? ((lo_start - v_res + 7) >> 3) : 0;
  const int ntot     = ndist + nloc;

  const int per = (ntot + nsplit - 1) / nsplit;
  const int i0  = split * per;
  const int i1  = min(ntot, i0 + per);

  // Q fragment: this lane's 32 dims [c*32, c*32+32)
  const float* qp = qg + ((size_t)(b * H_ + h)) * D_ + c * 32;
  float4 qf[8];
#pragma unroll
  for (int i = 0; i < 8; ++i) qf[i] = *(const float4*)(qp + i * 4);

  const float sm_scale = 0.08838834764831845f;  // 1/sqrt(128)
  float m_run = -INFINITY, l_run = 0.f, o0 = 0.f, o1 = 0.f;

  const int* bt = block_tables + b * NBLK_;

  // prefetch first block index
  int kp = 0, nb = 0;
  if (i0 < i1) {
    kp = (i0 < ndist) ? (v_res + (i0 << 3)) : (lo_start + (i0 - ndist));
    nb = bt[kp];
  }

  for (int i = i0; i < i1; ++i) {
    const int kp_cur = kp;
    const float* kb = kc + (size_t)(nb * KVH_ + kvh) * 2048;
    const float* vb = vc + (size_t)(nb * KVH_ + kvh) * 2048;

    // prefetch next block index (hides bt -> K/V dependency)
    const int in = i + 1;
    if (in < i1) {
      kp = (in < ndist) ? (v_res + (in << 3)) : (lo_start + (in - ndist));
      nb = bt[kp];
    }

    // ---- QK^T: lane computes partial dot over its 32 dims for token t ----
    float acc = 0.f;
#pragma unroll
    for (int ii = 0; ii < 8; ++ii) {
      float4 kk = *(const float4*)(kb + (c * 8 + ii) * 64 + t * 4);
      acc += qf[ii].x * kk.x + qf[ii].y * kk.y + qf[ii].z * kk.z + qf[ii].w * kk.w;
    }
    acc += __shfl_xor(acc, 1, 64);
    acc += __shfl_xor(acc, 2, 64);
    float s = acc * sm_scale;
    if (((kp_cur << 4) + t) > past_len) s = -INFINITY;  // token-level causal

    // ---- online softmax (reduce across token groups: xor 4,8,16,32) ----
    float bm = s;
#pragma unroll
    for (int mk = 4; mk < 64; mk <<= 1) bm = fmaxf(bm, __shfl_xor(bm, mk, 64));
    const float m_new = fmaxf(m_run, bm);
    const float corr  = __expf(m_run - m_new);  // exp(-inf) = 0
    const float p     = __expf(s - m_new);
    float psum = p;
#pragma unroll
    for (int mk = 4; mk < 64; mk <<= 1) psum += __shfl_xor(psum, mk, 64);
    l_run = l_run * corr + psum;
    m_run = m_new;
    o0 *= corr;
    o1 *= corr;

    // ---- PV: lane owns dims d0=lane, d1=lane+64 ----
    float pb[16];
#pragma unroll
    for (int tt = 0; tt < 16; ++tt) pb[tt] = __shfl(p, tt * 4, 64);
    const float* v0 = vb + lane * 16;
    const float* v1 = vb + (lane + 64) * 16;
#pragma unroll
    for (int ii = 0; ii < 4; ++ii) {
      float4 va  = *(const float4*)(v0 + ii * 4);
      float4 vbq = *(const float4*)(v1 + ii * 4);
      o0 += pb[ii * 4 + 0] * va.x + pb[ii * 4 + 1] * va.y +
            pb[ii * 4 + 2] * va.z + pb[ii * 4 + 3] * va.w;
      o1 += pb[ii * 4 + 0] * vbq.x + pb[ii * 4 + 1] * vbq.y +
            pb[ii * 4 + 2] * vbq.z + pb[ii * 4 + 3] * vbq.w;
    }
  }

  if (direct) {
    const float inv_l = (l_run > 0.f) ? (1.f / l_run) : 0.f;
    float* op = out + ((size_t)(b * H_ + h)) * D_;
    op[lane]      = o0 * inv_l;
    op[lane + 64] = o1 * inv_l;
  } else {
    float* pop = po + ((size_t)((b * H_ + h) * NSPLIT_ + split)) * D_;
    pop[lane]      = o0;
    pop[lane + 64] = o1;
    if (lane == 0) {
      float* pm = pml + ((size_t)((b * H_ + h) * NSPLIT_ + split)) * 2;
      pm[0] = m_run;
      pm[1] = l_run;
    }
  }
}

__global__ __launch_bounds__(256) void sparse_attn_partial16(
    const float* __restrict__ qg, const float* __restrict__ kc,
    const float* __restrict__ vc, const int* __restrict__ block_tables,
    const int* __restrict__ ctx_lens,
    float* __restrict__ po, float* __restrict__ pml)
{
  int bid = blockIdx.x;
  const int split = bid % NSPLIT_; bid /= NSPLIT_;
  const int kvh = bid % KVH_;
  const int b   = bid / KVH_;
  attn_body(qg, kc, vc, block_tables, ctx_lens, NSPLIT_, split, b, kvh,
            po, pml, nullptr, false);
}

__global__ __launch_bounds__(256) void sparse_attn_direct(
    const float* __restrict__ qg, const float* __restrict__ kc,
    const float* __restrict__ vc, const int* __restrict__ block_tables,
    const int* __restrict__ ctx_lens, float* __restrict__ out)
{
  int bid = blockIdx.x;
  const int kvh = bid % KVH_;
  const int b   = bid / KVH_;
  attn_body(qg, kc, vc, block_tables, ctx_lens, 1, 0, b, kvh,
            nullptr, nullptr, out, true);
}

__global__ __launch_bounds__(128) void sparse_attn_combine16(
    const float* __restrict__ po, const float* __restrict__ pml,
    float* __restrict__ out)
{
  const int bh = blockIdx.x;   // 0 .. B*H-1
  const int d  = threadIdx.x;  // 0 .. 127
  const float* pm = pml + (size_t)bh * NSPLIT_ * 2;
  float m_g = -INFINITY;
#pragma unroll
  for (int s = 0; s < NSPLIT_; ++s) m_g = fmaxf(m_g, pm[s * 2]);
  float L = 0.f, acc = 0.f;
  const float* pop = po + (size_t)bh * NSPLIT_ * D_ + d;
#pragma unroll
  for (int s = 0; s < NSPLIT_; ++s) {
    const float ms = pm[s * 2];
    const float sc = (ms == -INFINITY) ? 0.f : __expf(ms - m_g);
    L += pm[s * 2 + 1] * sc;
    acc += pop[s * D_] * sc;
  }
  out[(size_t)bh * D_ + d] = acc / L;
}

extern "C" void kernel_launch(void* const* d_in, const int* in_sizes, int n_in,
                              void* d_out, int out_size, void* d_ws, size_t ws_size,
                              hipStream_t stream) {
  const float* q  = (const float*)d_in[0];
  const float* k  = (const float*)d_in[1];
  const float* v  = (const float*)d_in[2];
  const int* bt   = (const int*)d_in[3];
  const int* cl   = (const int*)d_in[4];
  // d_in[5] (pattern) is recomputed analytically on device.
  float* out = (float*)d_out;

  const size_t needed = (size_t)B_ * H_ * NSPLIT_ * (D_ + 2) * sizeof(float);

  if (ws_size >= needed) {
    float* po  = (float*)d_ws;                        // [B,H,NSPLIT,D]
    float* pml = po + (size_t)B_ * H_ * NSPLIT_ * D_; // [B,H,NSPLIT,2]
    hipLaunchKernelGGL(sparse_attn_partial16,
                       dim3(B_ * KVH_ * NSPLIT_), dim3(256), 0, stream,
                       q, k, v, bt, cl, po, pml);
    hipLaunchKernelGGL(sparse_attn_combine16,
                       dim3(B_ * H_), dim3(128), 0, stream, po, pml, out);
  } else {
    hipLaunchKernelGGL(sparse_attn_direct,
                       dim3(B_ * KVH_), dim3(256), 0, stream,
                       q, k, v, bt, cl, out);
  }
}

// Round 6
// 457.871 us; speedup vs baseline: 1.0110x; 1.0110x over previous
//
#include <hip/hip_runtime.h>
#include <hip/hip_bf16.h>
#include <math.h>

// Problem constants: B=16, H=32, KV=8, D=128, BS=16, MAXLEN=4096
#define B_ 16
#define H_ 32
#define KVH_ 8
#define D_ 128
#define BS_ 16
#define NBLK_ 256
#define GQA_R 4          // H / KV
#define LOCALB 16        // LOCAL_BLOCKS
#define VSTRIDE 8        // VERT_STRIDE (head_sliding_step = max(1, 8/32) = 1)
#define NSPLIT_ 16

// K layout: [NB][KVH][D/4][BS][4] f32 -> K[t][d] at (((nb*8+kvh)*32 + d/4)*16 + t)*4 + d%4
// V layout: [NB][KVH][D][BS]   f32 -> V[d][t] at  ((nb*8+kvh)*128 + d)*16 + t
// Both are 2048 floats (8KB) per (nb,kvh).

__device__ __forceinline__ float dot32(const float4* __restrict__ kp,
                                       const float4 qf[8]) {
  float acc = 0.f;
#pragma unroll
  for (int ii = 0; ii < 8; ++ii) {
    float4 kk = kp[ii * 16];  // stride 64 floats = 16 float4
    acc += qf[ii].x * kk.x + qf[ii].y * kk.y + qf[ii].z * kk.z + qf[ii].w * kk.w;
  }
  return acc;
}

__device__ __forceinline__ void attn_body(
    const float* __restrict__ qg, const float* __restrict__ kc,
    const float* __restrict__ vc, const int* __restrict__ block_tables,
    const int* __restrict__ ctx_lens,
    int nsplit, int split, int b, int kvh,
    float* __restrict__ po, float* __restrict__ pml, float* __restrict__ out,
    bool direct)
{
  const int wid  = threadIdx.x >> 6;   // wave = head-in-group
  const int lane = threadIdx.x & 63;
  const int t    = lane >> 2;          // token 0..15
  const int c    = lane & 3;           // 32-dim chunk 0..3
  const int h    = kvh * GQA_R + wid;

  const int past_len = ctx_lens[b] - 1;
  const int q_pbid   = past_len >> 4;
  const int lo_start = max(0, q_pbid - (LOCALB - 1));
  const int nloc     = q_pbid - lo_start + 1;
  const int v_res    = (VSTRIDE - ((h + 1) & (VSTRIDE - 1))) & (VSTRIDE - 1);
  const int ndist    = (lo_start > v_res) ? ((lo_start - v_res + 7) >> 3) : 0;
  const int ntot     = ndist + nloc;

  const int per = (ntot + nsplit - 1) / nsplit;
  const int i0  = split * per;
  const int i1  = min(ntot, i0 + per);

  // Q fragment: this lane's 32 dims [c*32, c*32+32)
  const float* qp = qg + ((size_t)(b * H_ + h)) * D_ + c * 32;
  float4 qf[8];
#pragma unroll
  for (int i = 0; i < 8; ++i) qf[i] = *(const float4*)(qp + i * 4);

  const float sm_scale = 0.08838834764831845f;  // 1/sqrt(128)
  float m_run = -INFINITY, l_run = 0.f, o0 = 0.f, o1 = 0.f;

  const int* bt = block_tables + b * NBLK_;
  const int koff = c * 512 + t * 4;   // per-lane K offset (floats)

  int i = i0;

  // ---- pair loop: 2 KV blocks per iteration, joint softmax update ----
  for (; i + 1 < i1; i += 2) {
    const int kp0 = (i < ndist) ? (v_res + (i << 3)) : (lo_start + (i - ndist));
    const int j = i + 1;
    const int kp1 = (j < ndist) ? (v_res + (j << 3)) : (lo_start + (j - ndist));
    const int nb0 = bt[kp0];
    const int nb1 = bt[kp1];
    const float* kb0 = kc + (size_t)(nb0 * KVH_ + kvh) * 2048;
    const float* kb1 = kc + (size_t)(nb1 * KVH_ + kvh) * 2048;
    const float* vb0 = vc + (size_t)(nb0 * KVH_ + kvh) * 2048;
    const float* vb1 = vc + (size_t)(nb1 * KVH_ + kvh) * 2048;

    // two independent QK^T chains (memory latencies overlap)
    float acc0 = dot32((const float4*)(kb0 + koff), qf);
    float acc1 = dot32((const float4*)(kb1 + koff), qf);
    acc0 += __shfl_xor(acc0, 1, 64);
    acc1 += __shfl_xor(acc1, 1, 64);
    acc0 += __shfl_xor(acc0, 2, 64);
    acc1 += __shfl_xor(acc1, 2, 64);
    float s0 = acc0 * sm_scale;
    float s1 = acc1 * sm_scale;
    if (((kp0 << 4) + t) > past_len) s0 = -INFINITY;
    if (((kp1 << 4) + t) > past_len) s1 = -INFINITY;

    // ONE shared max tree + ONE shared sum tree for the pair
    float bm = fmaxf(s0, s1);
#pragma unroll
    for (int mk = 4; mk < 64; mk <<= 1) bm = fmaxf(bm, __shfl_xor(bm, mk, 64));
    const float m_new = fmaxf(m_run, bm);
    const float corr  = __expf(m_run - m_new);
    const float p0    = __expf(s0 - m_new);
    const float p1    = __expf(s1 - m_new);
    float psum = p0 + p1;
#pragma unroll
    for (int mk = 4; mk < 64; mk <<= 1) psum += __shfl_xor(psum, mk, 64);
    l_run = l_run * corr + psum;
    m_run = m_new;
    o0 *= corr;
    o1 *= corr;

    // broadcasts (independent -> pipelined)
    float pb0[16], pb1[16];
#pragma unroll
    for (int tt = 0; tt < 16; ++tt) {
      pb0[tt] = __shfl(p0, tt * 4, 64);
      pb1[tt] = __shfl(p1, tt * 4, 64);
    }

    const float* v00 = vb0 + lane * 16;
    const float* v01 = vb0 + (lane + 64) * 16;
    const float* v10 = vb1 + lane * 16;
    const float* v11 = vb1 + (lane + 64) * 16;
#pragma unroll
    for (int ii = 0; ii < 4; ++ii) {
      float4 a0 = *(const float4*)(v00 + ii * 4);
      float4 a1 = *(const float4*)(v01 + ii * 4);
      float4 b0 = *(const float4*)(v10 + ii * 4);
      float4 b1 = *(const float4*)(v11 + ii * 4);
      o0 += pb0[ii * 4 + 0] * a0.x + pb0[ii * 4 + 1] * a0.y +
            pb0[ii * 4 + 2] * a0.z + pb0[ii * 4 + 3] * a0.w;
      o1 += pb0[ii * 4 + 0] * a1.x + pb0[ii * 4 + 1] * a1.y +
            pb0[ii * 4 + 2] * a1.z + pb0[ii * 4 + 3] * a1.w;
      o0 += pb1[ii * 4 + 0] * b0.x + pb1[ii * 4 + 1] * b0.y +
            pb1[ii * 4 + 2] * b0.z + pb1[ii * 4 + 3] * b0.w;
      o1 += pb1[ii * 4 + 0] * b1.x + pb1[ii * 4 + 1] * b1.y +
            pb1[ii * 4 + 2] * b1.z + pb1[ii * 4 + 3] * b1.w;
    }
  }

  // ---- tail: single block ----
  if (i < i1) {
    const int kp = (i < ndist) ? (v_res + (i << 3)) : (lo_start + (i - ndist));
    const int nb = bt[kp];
    const float* kb = kc + (size_t)(nb * KVH_ + kvh) * 2048;
    const float* vb = vc + (size_t)(nb * KVH_ + kvh) * 2048;

    float acc = dot32((const float4*)(kb + koff), qf);
    acc += __shfl_xor(acc, 1, 64);
    acc += __shfl_xor(acc, 2, 64);
    float s = acc * sm_scale;
    if (((kp << 4) + t) > past_len) s = -INFINITY;

    float bm = s;
#pragma unroll
    for (int mk = 4; mk < 64; mk <<= 1) bm = fmaxf(bm, __shfl_xor(bm, mk, 64));
    const float m_new = fmaxf(m_run, bm);
    const float corr  = __expf(m_run - m_new);
    const float p     = __expf(s - m_new);
    float psum = p;
#pragma unroll
    for (int mk = 4; mk < 64; mk <<= 1) psum += __shfl_xor(psum, mk, 64);
    l_run = l_run * corr + psum;
    m_run = m_new;
    o0 *= corr;
    o1 *= corr;

    float pb[16];
#pragma unroll
    for (int tt = 0; tt < 16; ++tt) pb[tt] = __shfl(p, tt * 4, 64);
    const float* v0 = vb + lane * 16;
    const float* v1 = vb + (lane + 64) * 16;
#pragma unroll
    for (int ii = 0; ii < 4; ++ii) {
      float4 va  = *(const float4*)(v0 + ii * 4);
      float4 vbq = *(const float4*)(v1 + ii * 4);
      o0 += pb[ii * 4 + 0] * va.x + pb[ii * 4 + 1] * va.y +
            pb[ii * 4 + 2] * va.z + pb[ii * 4 + 3] * va.w;
      o1 += pb[ii * 4 + 0] * vbq.x + pb[ii * 4 + 1] * vbq.y +
            pb[ii * 4 + 2] * vbq.z + pb[ii * 4 + 3] * vbq.w;
    }
  }

  if (direct) {
    const float inv_l = (l_run > 0.f) ? (1.f / l_run) : 0.f;
    float* op = out + ((size_t)(b * H_ + h)) * D_;
    op[lane]      = o0 * inv_l;
    op[lane + 64] = o1 * inv_l;
  } else {
    float* pop = po + ((size_t)((b * H_ + h) * NSPLIT_ + split)) * D_;
    pop[lane]      = o0;
    pop[lane + 64] = o1;
    if (lane == 0) {
      float* pm = pml + ((size_t)((b * H_ + h) * NSPLIT_ + split)) * 2;
      pm[0] = m_run;
      pm[1] = l_run;
    }
  }
}

__global__ __launch_bounds__(256) void sparse_attn_partial16(
    const float* __restrict__ qg, const float* __restrict__ kc,
    const float* __restrict__ vc, const int* __restrict__ block_tables,
    const int* __restrict__ ctx_lens,
    float* __restrict__ po, float* __restrict__ pml)
{
  int bid = blockIdx.x;
  const int split = bid % NSPLIT_; bid /= NSPLIT_;
  const int kvh = bid % KVH_;
  const int b   = bid / KVH_;
  attn_body(qg, kc, vc, block_tables, ctx_lens, NSPLIT_, split, b, kvh,
            po, pml, nullptr, false);
}

__global__ __launch_bounds__(256) void sparse_attn_direct(
    const float* __restrict__ qg, const float* __restrict__ kc,
    const float* __restrict__ vc, const int* __restrict__ block_tables,
    const int* __restrict__ ctx_lens, float* __restrict__ out)
{
  int bid = blockIdx.x;
  const int kvh = bid % KVH_;
  const int b   = bid / KVH_;
  attn_body(qg, kc, vc, block_tables, ctx_lens, 1, 0, b, kvh,
            nullptr, nullptr, out, true);
}

__global__ __launch_bounds__(128) void sparse_attn_combine16(
    const float* __restrict__ po, const float* __restrict__ pml,
    float* __restrict__ out)
{
  const int bh = blockIdx.x;   // 0 .. B*H-1
  const int d  = threadIdx.x;  // 0 .. 127
  const float* pm = pml + (size_t)bh * NSPLIT_ * 2;
  float m_g = -INFINITY;
#pragma unroll
  for (int s = 0; s < NSPLIT_; ++s) m_g = fmaxf(m_g, pm[s * 2]);
  float L = 0.f, acc = 0.f;
  const float* pop = po + (size_t)bh * NSPLIT_ * D_ + d;
#pragma unroll
  for (int s = 0; s < NSPLIT_; ++s) {
    const float ms = pm[s * 2];
    const float sc = (ms == -INFINITY) ? 0.f : __expf(ms - m_g);
    L += pm[s * 2 + 1] * sc;
    acc += pop[s * D_] * sc;
  }
  out[(size_t)bh * D_ + d] = acc / L;
}

extern "C" void kernel_launch(void* const* d_in, const int* in_sizes, int n_in,
                              void* d_out, int out_size, void* d_ws, size_t ws_size,
                              hipStream_t stream) {
  const float* q  = (const float*)d_in[0];
  const float* k  = (const float*)d_in[1];
  const float* v  = (const float*)d_in[2];
  const int* bt   = (const int*)d_in[3];
  const int* cl   = (const int*)d_in[4];
  // d_in[5] (pattern) is recomputed analytically on device.
  float* out = (float*)d_out;

  const size_t needed = (size_t)B_ * H_ * NSPLIT_ * (D_ + 2) * sizeof(float);

  if (ws_size >= needed) {
    float* po  = (float*)d_ws;                        // [B,H,NSPLIT,D]
    float* pml = po + (size_t)B_ * H_ * NSPLIT_ * D_; // [B,H,NSPLIT,2]
    hipLaunchKernelGGL(sparse_attn_partial16,
                       dim3(B_ * KVH_ * NSPLIT_), dim3(256), 0, stream,
                       q, k, v, bt, cl, po, pml);
    hipLaunchKernelGGL(sparse_attn_combine16,
                       dim3(B_ * H_), dim3(128), 0, stream, po, pml, out);
  } else {
    hipLaunchKernelGGL(sparse_attn_direct,
                       dim3(B_ * KVH_), dim3(256), 0, stream,
                       q, k, v, bt, cl, out);
  }
}